// Round 8
// baseline (310.439 us; speedup 1.0000x reference)
//
#include <hip/hip_runtime.h>
#include <hip/hip_bf16.h>

// Problem constants
#define BB   4
#define SS   2048
#define DIN  1024
#define DOUT 1024
#define NH   16
#define HDIM 64

typedef __hip_bfloat16 bf16;
typedef __attribute__((ext_vector_type(8))) short short8;   // bf16 MFMA A/B frag (4 VGPR)
typedef __attribute__((ext_vector_type(4))) float floatx4;  // MFMA C/D frag

#define AS1(p) ((const __attribute__((address_space(1))) void*)(p))
#define AS3(p) ((__attribute__((address_space(3))) void*)(p))

// ---------------------------------------------------------------- fused prep:
// bid [0,4096)      : cast x (f32 -> bf16), 8 elems/thread
// bid [4096,4864)   : build Wqkv^T tile (64x64 transpose + cast)
// bid [4864,5376)   : cast Wo (f32 -> bf16)
__global__ void prep_all_kernel(const float* __restrict__ x,
                                const float* __restrict__ Wq, const float* __restrict__ Wk,
                                const float* __restrict__ Wv, const float* __restrict__ Wo,
                                bf16* __restrict__ xb, bf16* __restrict__ wt,
                                bf16* __restrict__ wob) {
    __shared__ float tile[64][65];
    const int bid = blockIdx.x;
    const int tid = threadIdx.x;
    if (bid < 4096 || bid >= 4864) {
        const float* src = (bid < 4096) ? x : Wo;
        bf16* dst        = (bid < 4096) ? xb : wob;
        const int  rb    = (bid < 4096) ? bid : (bid - 4864);
        size_t i = ((size_t)rb * 256 + tid) * 8;
        float4 a = *(const float4*)(src + i);
        float4 b = *(const float4*)(src + i + 4);
        bf16 o[8] __attribute__((aligned(16)));
        o[0] = __float2bfloat16(a.x); o[1] = __float2bfloat16(a.y);
        o[2] = __float2bfloat16(a.z); o[3] = __float2bfloat16(a.w);
        o[4] = __float2bfloat16(b.x); o[5] = __float2bfloat16(b.y);
        o[6] = __float2bfloat16(b.z); o[7] = __float2bfloat16(b.w);
        *(short8*)(dst + i) = *(short8*)o;
        return;
    }
    // ---- prep Wqkv^T: rows = output col n, cols = k ----
    const int pb = bid - 4096;
    const int kt = pb & 15;             // 16 k-tiles
    const int nt = pb >> 4;             // 48 n-tiles
    const int k0 = kt * 64, n0 = nt * 64;
    const float* W = (n0 < 1024) ? Wq : (n0 < 2048 ? Wk : Wv);
    const int col0 = n0 & 1023;
    {
        const int kl = tid >> 2, nc = (tid & 3) * 16;
        const float* src = W + (size_t)(k0 + kl) * 1024 + col0 + nc;
        #pragma unroll
        for (int i = 0; i < 16; i += 4) {
            float4 v = *(const float4*)(src + i);
            tile[kl][nc + i + 0] = v.x; tile[kl][nc + i + 1] = v.y;
            tile[kl][nc + i + 2] = v.z; tile[kl][nc + i + 3] = v.w;
        }
    }
    __syncthreads();
    {
        const int nl = tid >> 2, kc = (tid & 3) * 16;
        bf16 o[16] __attribute__((aligned(16)));
        #pragma unroll
        for (int i = 0; i < 16; ++i) o[i] = __float2bfloat16(tile[kc + i][nl]);
        bf16* dst = wt + (size_t)(n0 + nl) * 1024 + k0 + kc;
        *(short8*)dst       = *(short8*)&o[0];
        *(short8*)(dst + 8) = *(short8*)&o[8];
    }
}

// ---------------------------------------------------------------- GEMM: C = A @ Bt^T
// R7 single-barrier double-buffered K-loop (flash-proven structure), BK=64, XOR chunk
// swizzle, V-part fused transpose-store to vt. Unchanged from R7 (it gained ~4 us).
template<int EPI>
__global__ __launch_bounds__(256) void gemm_bt_kernel(
    const bf16* __restrict__ A, const bf16* __restrict__ Bt,
    void* __restrict__ C, const float* __restrict__ bias, int K, int ldc,
    bf16* __restrict__ vt) {
    __shared__ __align__(16) bf16 As[2][128][64];
    __shared__ __align__(16) bf16 Bs[2][128][64];
    const int tid  = threadIdx.x;
    const int wave = tid >> 6, lane = tid & 63;
    const int lm   = lane & 15, quad = lane >> 4;
    const int wm   = (wave >> 1) * 64, wn = (wave & 1) * 64;
    const size_t rowA0 = (size_t)blockIdx.x * 128;
    const size_t rowB0 = (size_t)blockIdx.y * 128;

    const int srow8  = lane >> 3;            // row within 8-group == row&7
    const int schunk = (lane & 7) ^ srow8;   // pre-swizzled source chunk
    const int sw     = lm & 7;               // read-side row&7

    floatx4 acc[4][4] = {};

    // prologue: stage tile 0 -> buf 0 (first loop barrier waits for it)
    #pragma unroll
    for (int j = 0; j < 4; ++j) {
        const int rbase = (wave * 4 + j) * 8;
        const bf16* gA = A  + (rowA0 + rbase + srow8) * (size_t)K + schunk * 8;
        __builtin_amdgcn_global_load_lds(AS1(gA), AS3(&As[0][rbase][0]), 16, 0, 0);
        const bf16* gB = Bt + (rowB0 + rbase + srow8) * (size_t)K + schunk * 8;
        __builtin_amdgcn_global_load_lds(AS1(gB), AS3(&Bs[0][rbase][0]), 16, 0, 0);
    }

    const int nk = K >> 6;
    #pragma unroll 1
    for (int t = 0; t < nk; ++t) {
        const int cur = t & 1;
        __syncthreads();   // tile t landed (vmcnt drain); buf^1 readers done (lgkm drain)
        if (t + 1 < nk) {
            #pragma unroll
            for (int j = 0; j < 4; ++j) {
                const int rbase = (wave * 4 + j) * 8;
                const bf16* gA = A  + (rowA0 + rbase + srow8) * (size_t)K + (t + 1) * 64 + schunk * 8;
                __builtin_amdgcn_global_load_lds(AS1(gA), AS3(&As[cur ^ 1][rbase][0]), 16, 0, 0);
                const bf16* gB = Bt + (rowB0 + rbase + srow8) * (size_t)K + (t + 1) * 64 + schunk * 8;
                __builtin_amdgcn_global_load_lds(AS1(gB), AS3(&Bs[cur ^ 1][rbase][0]), 16, 0, 0);
            }
        }
        short8 a[4][2], b[4][2];
        #pragma unroll
        for (int i = 0; i < 4; ++i) {
            const int r = wm + i * 16 + lm;
            a[i][0] = *(const short8*)&As[cur][r][((quad    ) ^ sw) * 8];
            a[i][1] = *(const short8*)&As[cur][r][((quad + 4) ^ sw) * 8];
        }
        #pragma unroll
        for (int j = 0; j < 4; ++j) {
            const int r = wn + j * 16 + lm;
            b[j][0] = *(const short8*)&Bs[cur][r][((quad    ) ^ sw) * 8];
            b[j][1] = *(const short8*)&Bs[cur][r][((quad + 4) ^ sw) * 8];
        }
        __builtin_amdgcn_s_setprio(1);
        #pragma unroll
        for (int i = 0; i < 4; ++i)
            #pragma unroll
            for (int j = 0; j < 4; ++j) {
                acc[i][j] = __builtin_amdgcn_mfma_f32_16x16x32_bf16(a[i][0], b[j][0], acc[i][j], 0, 0, 0);
                acc[i][j] = __builtin_amdgcn_mfma_f32_16x16x32_bf16(a[i][1], b[j][1], acc[i][j], 0, 0, 0);
            }
        __builtin_amdgcn_s_setprio(0);
    }

    if (EPI == 0 && rowB0 >= 2048) {
        // V-part: write transposed into vt[((b*16+h)*64+hd)*SS + s]; skip dead qkv store.
        #pragma unroll
        for (int i = 0; i < 4; ++i) {
            size_t row = rowA0 + wm + i * 16 + quad * 4;   // = b*2048 + s, 4-aligned
            const size_t b = row >> 11;
            const int    s = (int)(row & 2047);
            #pragma unroll
            for (int j = 0; j < 4; ++j) {
                const int col = (int)(rowB0 - 2048) + wn + j * 16 + lm;   // h*64 + hd
                bf16 o[4] __attribute__((aligned(8)));
                #pragma unroll
                for (int r = 0; r < 4; ++r) o[r] = __float2bfloat16(acc[i][j][r]);
                *(uint64_t*)(vt + ((b * 16 + (col >> 6)) * 64 + (col & 63)) * (size_t)SS + s)
                    = *(uint64_t*)o;
            }
        }
        return;
    }

    #pragma unroll
    for (int i = 0; i < 4; ++i) {
        size_t row = rowA0 + wm + i * 16 + quad * 4;
        #pragma unroll
        for (int j = 0; j < 4; ++j) {
            size_t col = rowB0 + wn + j * 16 + lm;
            float bv = (EPI == 1) ? bias[col] : 0.0f;
            #pragma unroll
            for (int r = 0; r < 4; ++r) {
                if (EPI == 0)
                    ((bf16*)C)[(row + r) * ldc + col] = __float2bfloat16(acc[i][j][r]);
                else
                    ((float*)C)[(row + r) * ldc + col] = acc[i][j][r] + bv;
            }
        }
    }
}

// ---------------------------------------------------------------- causal flash attention v9
// BARRIER-FREE: K/V fragments load directly from global (L2-resident by XCD swizzle:
// 8 bh x 512KB = 4MB per XCD). LDS K/V staging dropped (guide lesson #7: staging L2-fit
// data is pure overhead). Consequences:
//  - zero __syncthreads: waves fully independent; per-wave exact causal k-range
//    nkt = 2p+1+(wave>>1) (the R7 "skip" now saves real time — no barrier coupling);
//  - setprio now in its proven regime (m191: independent waves, +4-7%);
//  - P relay stays in per-wave LDS (intra-wave cross-lane; in-order DS pipe + compiler
//    lgkmcnt — never needed a barrier, byte-identical to v7's path);
//  - ka/va values/ordering identical to v7 -> bit-identical numerics.
// Frag-load coalescing: one short8 load = 16 rows x 64B fully-used lines (lanes 0-15 read
// rows at byte 0-15, lanes 16-31 bytes 16-31, ...). FETCH_SIZE counts HBM only -> flat
// FETCH = L2 absorbing re-reads (the confirming signal); FETCH jump = L2 thrash (revert).
// Occupancy governor: pad_ LDS (never-taken store, ctx alignment unprovable) caps at
// 3 blocks/CU so the 1024-block heavy-first grid keeps dynamic backfill (all-resident
// static assignment would suffer ~1.5x CU imbalance).
#define PSTR 68
__global__ __launch_bounds__(256, 3) void flash_attn_kernel(
    const bf16* __restrict__ qkv, const bf16* __restrict__ vt, bf16* __restrict__ ctx) {
    __shared__ __align__(16) bf16 Pl[4][32 * PSTR + 8]; // per-wave P (C->A layout), ~17.4 KB
    __shared__ char pad_[30720];                        // occupancy governor -> 3 blocks/CU
    const int tid  = threadIdx.x;
    const int wave = tid >> 6, lane = tid & 63;
    const int lm   = lane & 15, quad = lane >> 4;

    if (__builtin_expect(((size_t)ctx & 1) != 0, 0)) pad_[tid] = (char)lane;  // never true

    const int id  = blockIdx.x;          // 0..1023
    const int jl  = (id >> 3) & 7;
    const int bh  = (id & 7) * 8 + jl;   // 8 bh per XCD -> K/V L2-resident
    const int p   = 15 - (id >> 6);      // q-tile index, heavy first
    const int b = bh >> 4, h = bh & 15;

    const bf16* kg = qkv + (size_t)b * SS * 3072 + 1024 + h * 64;   // K base (row stride 3072)
    const bf16* vg = vt + (size_t)(b * NH + h) * 64 * SS;           // V^T base (row stride SS)

    bf16* Pw = &Pl[wave][0];

    const int qb  = p * 128 + wave * 32;          // wave's first q row
    const int nkt = 2 * p + 1 + (wave >> 1);      // exact per-wave causal k-range

    short8 bq[2][2];
    #pragma unroll
    for (int g = 0; g < 2; ++g) {
        const bf16* qp = qkv + ((size_t)(b * SS + qb + g * 16 + lm)) * 3072 + h * 64 + quad * 8;
        bq[g][0] = *(const short8*)qp;
        bq[g][1] = *(const short8*)(qp + 32);
    }

    floatx4 o[2][4] = {};
    float lsum[2] = {0.f, 0.f};

    #pragma unroll 1
    for (int kt = 0; kt < nkt; ++kt) {
        // K A-frags + V B-frags direct from L2 (same values/layout as the staged path)
        short8 ka[4][2], va[4][2];
        #pragma unroll
        for (int nt = 0; nt < 4; ++nt) {
            const bf16* kr = kg + (size_t)(kt * 64 + nt * 16 + lm) * 3072 + quad * 8;
            ka[nt][0] = *(const short8*)kr;
            ka[nt][1] = *(const short8*)(kr + 32);
            const bf16* vr = vg + (size_t)(nt * 16 + lm) * SS + kt * 64 + quad * 8;
            va[nt][0] = *(const short8*)vr;
            va[nt][1] = *(const short8*)(vr + 32);
        }

        #pragma unroll
        for (int g = 0; g < 2; ++g) {
            floatx4 sc[4];
            __builtin_amdgcn_s_setprio(1);
            #pragma unroll
            for (int nt = 0; nt < 4; ++nt) {
                floatx4 z = {};
                z = __builtin_amdgcn_mfma_f32_16x16x32_bf16(ka[nt][0], bq[g][0], z, 0, 0, 0);
                z = __builtin_amdgcn_mfma_f32_16x16x32_bf16(ka[nt][1], bq[g][1], z, 0, 0, 0);
                sc[nt] = z;
            }
            __builtin_amdgcn_s_setprio(0);
            if (kt * 64 + 63 > qb + g * 16) {
                const int qrow = qb + g * 16 + lm;
                #pragma unroll
                for (int nt = 0; nt < 4; ++nt)
                    #pragma unroll
                    for (int r = 0; r < 4; ++r)
                        if (kt * 64 + nt * 16 + quad * 4 + r > qrow) sc[nt][r] = -1e30f;
            }
            #pragma unroll
            for (int nt = 0; nt < 4; ++nt) {
                bf16 pk[4] __attribute__((aligned(8)));
                #pragma unroll
                for (int r = 0; r < 4; ++r) {
                    float pv = __builtin_amdgcn_exp2f(sc[nt][r] * 0.18033688f);
                    lsum[g] += pv;
                    pk[r] = __float2bfloat16(pv);
                }
                *(uint64_t*)&Pw[(g * 16 + lm) * PSTR + nt * 16 + quad * 4] = *(uint64_t*)pk;
            }
        }
        #pragma unroll
        for (int g = 0; g < 2; ++g) {
            const short8 ap0 = *(const short8*)&Pw[(g * 16 + lm) * PSTR + quad * 8];
            const short8 ap1 = *(const short8*)&Pw[(g * 16 + lm) * PSTR + 32 + quad * 8];
            __builtin_amdgcn_s_setprio(1);
            #pragma unroll
            for (int t = 0; t < 4; ++t) {
                o[g][t] = __builtin_amdgcn_mfma_f32_16x16x32_bf16(ap0, va[t][0], o[g][t], 0, 0, 0);
                o[g][t] = __builtin_amdgcn_mfma_f32_16x16x32_bf16(ap1, va[t][1], o[g][t], 0, 0, 0);
            }
            __builtin_amdgcn_s_setprio(0);
        }
    }

    #pragma unroll
    for (int g = 0; g < 2; ++g) {
        float rsum = lsum[g];
        rsum += __shfl_xor(rsum, 16);
        rsum += __shfl_xor(rsum, 32);
        float rl[4];
        #pragma unroll
        for (int r = 0; r < 4; ++r) rl[r] = 1.0f / __shfl(rsum, quad * 4 + r);
        #pragma unroll
        for (int t = 0; t < 4; ++t)
            #pragma unroll
            for (int r = 0; r < 4; ++r) {
                size_t row = (size_t)b * SS + qb + g * 16 + quad * 4 + r;
                ctx[row * 1024 + h * 64 + t * 16 + lm] = __float2bfloat16(o[g][t][r] * rl[r]);
            }
    }
}

// ---------------------------------------------------------------- launch (4 dispatches)
extern "C" void kernel_launch(void* const* d_in, const int* in_sizes, int n_in,
                              void* d_out, int out_size, void* d_ws, size_t ws_size,
                              hipStream_t stream) {
    const float* x  = (const float*)d_in[0];
    const float* Wq = (const float*)d_in[1];
    const float* Wk = (const float*)d_in[2];
    const float* Wv = (const float*)d_in[3];
    const float* Wo = (const float*)d_in[4];
    const float* bo = (const float*)d_in[5];

    char* ws = (char*)d_ws;
    bf16* xb  = (bf16*)ws;  ws += (size_t)8192 * 1024 * 2;   // 16 MB (reused as ctx)
    bf16* wt  = (bf16*)ws;  ws += (size_t)3072 * 1024 * 2;   //  6 MB
    bf16* wob = (bf16*)ws;  ws += (size_t)1024 * 1024 * 2;   //  2 MB
    bf16* qkv = (bf16*)ws;  ws += (size_t)8192 * 3072 * 2;   // 48 MB (V third dead/unwritten)
    bf16* vtb = (bf16*)ws;  ws += (size_t)BB * NH * HDIM * SS * 2;  // 16 MB
    bf16* ctx = xb;  // xb dead after gemm_qkv -> alias

    prep_all_kernel<<<5376, 256, 0, stream>>>(x, Wq, Wk, Wv, Wo, xb, wt, wob);
    gemm_bt_kernel<0><<<dim3(64, 24), 256, 0, stream>>>(xb, wt, (void*)qkv, nullptr, 1024, 3072, vtb);
    flash_attn_kernel<<<1024, 256, 0, stream>>>(qkv, vtb, ctx);
    gemm_bt_kernel<1><<<dim3(64, 8), 256, 0, stream>>>(ctx, wob, d_out, bo, 1024, 1024, nullptr);
}

// Round 9
// 245.169 us; speedup vs baseline: 1.2662x; 1.2662x over previous
//
#include <hip/hip_runtime.h>
#include <hip/hip_bf16.h>

// Problem constants
#define BB   4
#define SS   2048
#define DIN  1024
#define DOUT 1024
#define NH   16
#define HDIM 64

typedef __hip_bfloat16 bf16;
typedef __attribute__((ext_vector_type(8))) short short8;   // bf16 MFMA A/B frag (4 VGPR)
typedef __attribute__((ext_vector_type(4))) float floatx4;  // MFMA C/D frag

#define AS1(p) ((const __attribute__((address_space(1))) void*)(p))
#define AS3(p) ((__attribute__((address_space(3))) void*)(p))

// ---------------------------------------------------------------- fused prep:
// bid [0,4096)      : cast x (f32 -> bf16), 8 elems/thread
// bid [4096,4864)   : build Wqkv^T tile (64x64 transpose + cast)
// bid [4864,5376)   : cast Wo (f32 -> bf16)
__global__ void prep_all_kernel(const float* __restrict__ x,
                                const float* __restrict__ Wq, const float* __restrict__ Wk,
                                const float* __restrict__ Wv, const float* __restrict__ Wo,
                                bf16* __restrict__ xb, bf16* __restrict__ wt,
                                bf16* __restrict__ wob) {
    __shared__ float tile[64][65];
    const int bid = blockIdx.x;
    const int tid = threadIdx.x;
    if (bid < 4096 || bid >= 4864) {
        const float* src = (bid < 4096) ? x : Wo;
        bf16* dst        = (bid < 4096) ? xb : wob;
        const int  rb    = (bid < 4096) ? bid : (bid - 4864);
        size_t i = ((size_t)rb * 256 + tid) * 8;
        float4 a = *(const float4*)(src + i);
        float4 b = *(const float4*)(src + i + 4);
        bf16 o[8] __attribute__((aligned(16)));
        o[0] = __float2bfloat16(a.x); o[1] = __float2bfloat16(a.y);
        o[2] = __float2bfloat16(a.z); o[3] = __float2bfloat16(a.w);
        o[4] = __float2bfloat16(b.x); o[5] = __float2bfloat16(b.y);
        o[6] = __float2bfloat16(b.z); o[7] = __float2bfloat16(b.w);
        *(short8*)(dst + i) = *(short8*)o;
        return;
    }
    // ---- prep Wqkv^T: rows = output col n, cols = k ----
    const int pb = bid - 4096;
    const int kt = pb & 15;             // 16 k-tiles
    const int nt = pb >> 4;             // 48 n-tiles
    const int k0 = kt * 64, n0 = nt * 64;
    const float* W = (n0 < 1024) ? Wq : (n0 < 2048 ? Wk : Wv);
    const int col0 = n0 & 1023;
    {
        const int kl = tid >> 2, nc = (tid & 3) * 16;
        const float* src = W + (size_t)(k0 + kl) * 1024 + col0 + nc;
        #pragma unroll
        for (int i = 0; i < 16; i += 4) {
            float4 v = *(const float4*)(src + i);
            tile[kl][nc + i + 0] = v.x; tile[kl][nc + i + 1] = v.y;
            tile[kl][nc + i + 2] = v.z; tile[kl][nc + i + 3] = v.w;
        }
    }
    __syncthreads();
    {
        const int nl = tid >> 2, kc = (tid & 3) * 16;
        bf16 o[16] __attribute__((aligned(16)));
        #pragma unroll
        for (int i = 0; i < 16; ++i) o[i] = __float2bfloat16(tile[kc + i][nl]);
        bf16* dst = wt + (size_t)(n0 + nl) * 1024 + k0 + kc;
        *(short8*)dst       = *(short8*)&o[0];
        *(short8*)(dst + 8) = *(short8*)&o[8];
    }
}

// ---------------------------------------------------------------- GEMM: C = A @ Bt^T
// R7 single-barrier double-buffered K-loop (flash-proven structure), BK=64, XOR chunk
// swizzle, V-part fused transpose-store to vt. PROVEN R7 (gemms left the top-5).
template<int EPI>
__global__ __launch_bounds__(256) void gemm_bt_kernel(
    const bf16* __restrict__ A, const bf16* __restrict__ Bt,
    void* __restrict__ C, const float* __restrict__ bias, int K, int ldc,
    bf16* __restrict__ vt) {
    __shared__ __align__(16) bf16 As[2][128][64];
    __shared__ __align__(16) bf16 Bs[2][128][64];
    const int tid  = threadIdx.x;
    const int wave = tid >> 6, lane = tid & 63;
    const int lm   = lane & 15, quad = lane >> 4;
    const int wm   = (wave >> 1) * 64, wn = (wave & 1) * 64;
    const size_t rowA0 = (size_t)blockIdx.x * 128;
    const size_t rowB0 = (size_t)blockIdx.y * 128;

    const int srow8  = lane >> 3;            // row within 8-group == row&7
    const int schunk = (lane & 7) ^ srow8;   // pre-swizzled source chunk
    const int sw     = lm & 7;               // read-side row&7

    floatx4 acc[4][4] = {};

    // prologue: stage tile 0 -> buf 0 (first loop barrier waits for it)
    #pragma unroll
    for (int j = 0; j < 4; ++j) {
        const int rbase = (wave * 4 + j) * 8;
        const bf16* gA = A  + (rowA0 + rbase + srow8) * (size_t)K + schunk * 8;
        __builtin_amdgcn_global_load_lds(AS1(gA), AS3(&As[0][rbase][0]), 16, 0, 0);
        const bf16* gB = Bt + (rowB0 + rbase + srow8) * (size_t)K + schunk * 8;
        __builtin_amdgcn_global_load_lds(AS1(gB), AS3(&Bs[0][rbase][0]), 16, 0, 0);
    }

    const int nk = K >> 6;
    #pragma unroll 1
    for (int t = 0; t < nk; ++t) {
        const int cur = t & 1;
        __syncthreads();   // tile t landed (vmcnt drain); buf^1 readers done (lgkm drain)
        if (t + 1 < nk) {
            #pragma unroll
            for (int j = 0; j < 4; ++j) {
                const int rbase = (wave * 4 + j) * 8;
                const bf16* gA = A  + (rowA0 + rbase + srow8) * (size_t)K + (t + 1) * 64 + schunk * 8;
                __builtin_amdgcn_global_load_lds(AS1(gA), AS3(&As[cur ^ 1][rbase][0]), 16, 0, 0);
                const bf16* gB = Bt + (rowB0 + rbase + srow8) * (size_t)K + (t + 1) * 64 + schunk * 8;
                __builtin_amdgcn_global_load_lds(AS1(gB), AS3(&Bs[cur ^ 1][rbase][0]), 16, 0, 0);
            }
        }
        short8 a[4][2], b[4][2];
        #pragma unroll
        for (int i = 0; i < 4; ++i) {
            const int r = wm + i * 16 + lm;
            a[i][0] = *(const short8*)&As[cur][r][((quad    ) ^ sw) * 8];
            a[i][1] = *(const short8*)&As[cur][r][((quad + 4) ^ sw) * 8];
        }
        #pragma unroll
        for (int j = 0; j < 4; ++j) {
            const int r = wn + j * 16 + lm;
            b[j][0] = *(const short8*)&Bs[cur][r][((quad    ) ^ sw) * 8];
            b[j][1] = *(const short8*)&Bs[cur][r][((quad + 4) ^ sw) * 8];
        }
        __builtin_amdgcn_s_setprio(1);
        #pragma unroll
        for (int i = 0; i < 4; ++i)
            #pragma unroll
            for (int j = 0; j < 4; ++j) {
                acc[i][j] = __builtin_amdgcn_mfma_f32_16x16x32_bf16(a[i][0], b[j][0], acc[i][j], 0, 0, 0);
                acc[i][j] = __builtin_amdgcn_mfma_f32_16x16x32_bf16(a[i][1], b[j][1], acc[i][j], 0, 0, 0);
            }
        __builtin_amdgcn_s_setprio(0);
    }

    if (EPI == 0 && rowB0 >= 2048) {
        // V-part: write transposed into vt[((b*16+h)*64+hd)*SS + s]; skip dead qkv store.
        #pragma unroll
        for (int i = 0; i < 4; ++i) {
            size_t row = rowA0 + wm + i * 16 + quad * 4;   // = b*2048 + s, 4-aligned
            const size_t b = row >> 11;
            const int    s = (int)(row & 2047);
            #pragma unroll
            for (int j = 0; j < 4; ++j) {
                const int col = (int)(rowB0 - 2048) + wn + j * 16 + lm;   // h*64 + hd
                bf16 o[4] __attribute__((aligned(8)));
                #pragma unroll
                for (int r = 0; r < 4; ++r) o[r] = __float2bfloat16(acc[i][j][r]);
                *(uint64_t*)(vt + ((b * 16 + (col >> 6)) * 64 + (col & 63)) * (size_t)SS + s)
                    = *(uint64_t*)o;
            }
        }
        return;
    }

    #pragma unroll
    for (int i = 0; i < 4; ++i) {
        size_t row = rowA0 + wm + i * 16 + quad * 4;
        #pragma unroll
        for (int j = 0; j < 4; ++j) {
            size_t col = rowB0 + wn + j * 16 + lm;
            float bv = (EPI == 1) ? bias[col] : 0.0f;
            #pragma unroll
            for (int r = 0; r < 4; ++r) {
                if (EPI == 0)
                    ((bf16*)C)[(row + r) * ldc + col] = __float2bfloat16(acc[i][j][r]);
                else
                    ((float*)C)[(row + r) * ldc + col] = acc[i][j][r] + bv;
            }
        }
    }
}

// ---------------------------------------------------------------- causal flash attention v7
// REVERTED to the measured-best version (R1/R6: 74.1-74.3 us). R7's additions (masked-tile
// skip + setprio) cost ~2 us: skip saves nothing under barrier lockstep, and setprio in a
// 4-wave lockstep block is m190's regime (hurts). R8's barrier-free direct-L2 frag loads
// collapsed to 145 us: one frag-load = 16 cacheline transactions, x4 waves, ~200cy L2
// latency at low MLP (MfmaUtil 9.6) — LDS staging converts that into one coalesced DMA +
// conflict-free broadcast. Keep: grid 1024, 3 blocks/CU, heavy-first dispatch,
// single-barrier double-buffered K/V staging, XOR-swizzled chunks (0 conflicts).
#define PSTR 68
__global__ __launch_bounds__(256, 3) void flash_attn_kernel(
    const bf16* __restrict__ qkv, const bf16* __restrict__ vt, bf16* __restrict__ ctx) {
    __shared__ __align__(16) bf16 Ks[2][64 * 64];       // double-buffered K tile
    __shared__ __align__(16) bf16 Vs[2][64 * 64];       // double-buffered V tile
    __shared__ __align__(16) bf16 Pl[4][32 * PSTR + 8]; // per-wave P (C->A layout)
    const int tid  = threadIdx.x;
    const int wave = tid >> 6, lane = tid & 63;
    const int lm   = lane & 15, quad = lane >> 4;

    const int id  = blockIdx.x;          // 0..1023
    const int jl  = (id >> 3) & 7;
    const int bh  = (id & 7) * 8 + jl;
    const int p   = 15 - (id >> 6);      // q-tile index, heavy first
    const int b = bh >> 4, h = bh & 15;

    const int lane8r = lane >> 3;        // == row & 7
    const int schunk = (lane & 7) ^ lane8r;

    const bf16* kg = qkv + (size_t)b * SS * 3072 + 1024 + h * 64 + schunk * 8;
    const bf16* vg = vt + (size_t)(b * NH + h) * 64 * SS + schunk * 8;

    bf16* Pw = &Pl[wave][0];

    const int qb = p * 128 + wave * 32;      // wave's first q row
    const int nkt = 2 * p + 2;

    short8 bq[2][2];
    #pragma unroll
    for (int g = 0; g < 2; ++g) {
        const bf16* qp = qkv + ((size_t)(b * SS + qb + g * 16 + lm)) * 3072 + h * 64 + quad * 8;
        bq[g][0] = *(const short8*)qp;
        bq[g][1] = *(const short8*)(qp + 32);
    }

    floatx4 o[2][4] = {};
    float lsum[2] = {0.f, 0.f};

    #pragma unroll
    for (int c = 0; c < 2; ++c) {
        const int row = c * 32 + wave * 8 + lane8r;
        __builtin_amdgcn_global_load_lds(AS1(kg + (size_t)row * 3072), AS3(&Ks[0][(c * 256 + wave * 64) * 8]), 16, 0, 0);
        __builtin_amdgcn_global_load_lds(AS1(vg + (size_t)row * SS), AS3(&Vs[0][(c * 256 + wave * 64) * 8]), 16, 0, 0);
    }

    #pragma unroll 1
    for (int kt = 0; kt < nkt; ++kt) {
        const int cur = kt & 1;
        __syncthreads();   // tile kt arrived (vmcnt drain); buf^1 readers done
        if (kt + 1 < nkt) {
            #pragma unroll
            for (int c = 0; c < 2; ++c) {
                const int row = c * 32 + wave * 8 + lane8r;
                __builtin_amdgcn_global_load_lds(AS1(kg + (size_t)((kt + 1) * 64 + row) * 3072),
                                                 AS3(&Ks[cur ^ 1][(c * 256 + wave * 64) * 8]), 16, 0, 0);
                __builtin_amdgcn_global_load_lds(AS1(vg + (size_t)row * SS + (kt + 1) * 64),
                                                 AS3(&Vs[cur ^ 1][(c * 256 + wave * 64) * 8]), 16, 0, 0);
            }
        }

        const int sw = lm & 7;
        const bf16* Ksb = &Ks[cur][0];
        const bf16* Vsb = &Vs[cur][0];
        short8 ka[4][2], va[4][2];
        #pragma unroll
        for (int nt = 0; nt < 4; ++nt) {
            const int r0 = (nt * 16 + lm) * 64;
            ka[nt][0] = *(const short8*)(Ksb + r0 + ((quad ^ sw) * 8));
            ka[nt][1] = *(const short8*)(Ksb + r0 + (((4 + quad) ^ sw) * 8));
            va[nt][0] = *(const short8*)(Vsb + r0 + ((quad ^ sw) * 8));
            va[nt][1] = *(const short8*)(Vsb + r0 + (((4 + quad) ^ sw) * 8));
        }

        #pragma unroll
        for (int g = 0; g < 2; ++g) {
            floatx4 sc[4];
            #pragma unroll
            for (int nt = 0; nt < 4; ++nt) {
                floatx4 z = {};
                z = __builtin_amdgcn_mfma_f32_16x16x32_bf16(ka[nt][0], bq[g][0], z, 0, 0, 0);
                z = __builtin_amdgcn_mfma_f32_16x16x32_bf16(ka[nt][1], bq[g][1], z, 0, 0, 0);
                sc[nt] = z;
            }
            if (kt * 64 + 63 > qb + g * 16) {
                const int qrow = qb + g * 16 + lm;
                #pragma unroll
                for (int nt = 0; nt < 4; ++nt)
                    #pragma unroll
                    for (int r = 0; r < 4; ++r)
                        if (kt * 64 + nt * 16 + quad * 4 + r > qrow) sc[nt][r] = -1e30f;
            }
            #pragma unroll
            for (int nt = 0; nt < 4; ++nt) {
                bf16 pk[4] __attribute__((aligned(8)));
                #pragma unroll
                for (int r = 0; r < 4; ++r) {
                    float pv = __builtin_amdgcn_exp2f(sc[nt][r] * 0.18033688f);
                    lsum[g] += pv;
                    pk[r] = __float2bfloat16(pv);
                }
                *(uint64_t*)&Pw[(g * 16 + lm) * PSTR + nt * 16 + quad * 4] = *(uint64_t*)pk;
            }
        }
        #pragma unroll
        for (int g = 0; g < 2; ++g) {
            const short8 ap0 = *(const short8*)&Pw[(g * 16 + lm) * PSTR + quad * 8];
            const short8 ap1 = *(const short8*)&Pw[(g * 16 + lm) * PSTR + 32 + quad * 8];
            #pragma unroll
            for (int t = 0; t < 4; ++t) {
                o[g][t] = __builtin_amdgcn_mfma_f32_16x16x32_bf16(ap0, va[t][0], o[g][t], 0, 0, 0);
                o[g][t] = __builtin_amdgcn_mfma_f32_16x16x32_bf16(ap1, va[t][1], o[g][t], 0, 0, 0);
            }
        }
    }

    #pragma unroll
    for (int g = 0; g < 2; ++g) {
        float rsum = lsum[g];
        rsum += __shfl_xor(rsum, 16);
        rsum += __shfl_xor(rsum, 32);
        float rl[4];
        #pragma unroll
        for (int r = 0; r < 4; ++r) rl[r] = 1.0f / __shfl(rsum, quad * 4 + r);
        #pragma unroll
        for (int t = 0; t < 4; ++t)
            #pragma unroll
            for (int r = 0; r < 4; ++r) {
                size_t row = (size_t)b * SS + qb + g * 16 + quad * 4 + r;
                ctx[row * 1024 + h * 64 + t * 16 + lm] = __float2bfloat16(o[g][t][r] * rl[r]);
            }
    }
}

// ---------------------------------------------------------------- launch (4 dispatches)
extern "C" void kernel_launch(void* const* d_in, const int* in_sizes, int n_in,
                              void* d_out, int out_size, void* d_ws, size_t ws_size,
                              hipStream_t stream) {
    const float* x  = (const float*)d_in[0];
    const float* Wq = (const float*)d_in[1];
    const float* Wk = (const float*)d_in[2];
    const float* Wv = (const float*)d_in[3];
    const float* Wo = (const float*)d_in[4];
    const float* bo = (const float*)d_in[5];

    char* ws = (char*)d_ws;
    bf16* xb  = (bf16*)ws;  ws += (size_t)8192 * 1024 * 2;   // 16 MB (reused as ctx)
    bf16* wt  = (bf16*)ws;  ws += (size_t)3072 * 1024 * 2;   //  6 MB
    bf16* wob = (bf16*)ws;  ws += (size_t)1024 * 1024 * 2;   //  2 MB
    bf16* qkv = (bf16*)ws;  ws += (size_t)8192 * 3072 * 2;   // 48 MB (V third dead/unwritten)
    bf16* vtb = (bf16*)ws;  ws += (size_t)BB * NH * HDIM * SS * 2;  // 16 MB
    bf16* ctx = xb;  // xb dead after gemm_qkv -> alias

    prep_all_kernel<<<5376, 256, 0, stream>>>(x, Wq, Wk, Wv, Wo, xb, wt, wob);
    gemm_bt_kernel<0><<<dim3(64, 24), 256, 0, stream>>>(xb, wt, (void*)qkv, nullptr, 1024, 3072, vtb);
    flash_attn_kernel<<<1024, 256, 0, stream>>>(qkv, vtb, ctx);
    gemm_bt_kernel<1><<<dim3(64, 8), 256, 0, stream>>>(ctx, wob, d_out, bo, 1024, 1024, nullptr);
}